// Round 3
// baseline (103.735 us; speedup 1.0000x reference)
//
#include <hip/hip_runtime.h>
#include <hip/hip_bf16.h>
#include <cstdint>

// GAT fused layer: B=4, N=2048, F=128, H=8, HD=16, all fp32 I/O.
// pack: adj -> u64 bitmasks [8192 rows][32 words] (2 MB), coalesced, read-once.
// proj: XW = x@W (fp32), emit WxT bf16 [B][128][N], e_i/e_j fp32 (pre-scaled
//       by log2 e), plus WoT = Wo^T.
// gat:  block = 16 rows x 8 heads x 2 j-halves (16 waves, 1024 thr);
//       barrier-free j-loop, scores as MFMA A-frags, aggregation + row-sum
//       via mfma (B=ones), pair-combine via LDS, fused out-proj + ELU.

typedef float f32x2 __attribute__((ext_vector_type(2)));
typedef float f32x4 __attribute__((ext_vector_type(4)));
typedef __bf16 bf16x8 __attribute__((ext_vector_type(8)));

#define LOG2E 1.44269504088896340736f

#if __has_builtin(__builtin_amdgcn_exp2f)
#define EXP2F(x) __builtin_amdgcn_exp2f(x)
#else
#define EXP2F(x) __expf((x) * 0.69314718055994531f)
#endif

__global__ __launch_bounds__(256)
void pack_kernel(const int* __restrict__ adj, unsigned long long* __restrict__ bits)
{
    const int wid = blockIdx.x * 4 + (threadIdx.x >> 6);  // row 0..8191
    const int lane = threadIdx.x & 63;
    const int* row = adj + (size_t)wid * 2048;
    unsigned long long* brow = bits + (size_t)wid * 32;
    #pragma unroll 2
    for (int it = 0; it < 8; ++it) {
        const int base = it * 256;
        const unsigned long long w0 = __ballot(row[base + lane] != 0);
        const unsigned long long w1 = __ballot(row[base + 64 + lane] != 0);
        const unsigned long long w2 = __ballot(row[base + 128 + lane] != 0);
        const unsigned long long w3 = __ballot(row[base + 192 + lane] != 0);
        if (lane == 0) {
            ulonglong2 p0; p0.x = w0; p0.y = w1;
            ulonglong2 p1; p1.x = w2; p1.y = w3;
            *reinterpret_cast<ulonglong2*>(&brow[it * 4])     = p0;
            *reinterpret_cast<ulonglong2*>(&brow[it * 4 + 2]) = p1;
        }
    }
}

__global__ __launch_bounds__(128)
void proj_kernel(const float* __restrict__ x, const float* __restrict__ W,
                 const float* __restrict__ a, const float* __restrict__ Wo,
                 unsigned short* __restrict__ wxT, float* __restrict__ ei,
                 float* __restrict__ ej, float* __restrict__ WoT)
{
    const int t = threadIdx.x;
    const int blk = blockIdx.x;
    if (blk == 1024) {
        for (int k = 0; k < 128; ++k)
            WoT[k * 128 + t] = Wo[t * 128 + k];
        return;
    }
    __shared__ float xl[8 * 128];
    __shared__ float xw[8 * 128];
    const int row0 = blk * 8;
    #pragma unroll
    for (int r = 0; r < 8; ++r)
        xl[r * 128 + t] = x[(size_t)(row0 + r) * 128 + t];
    __syncthreads();

    float acc[8] = {0.f, 0.f, 0.f, 0.f, 0.f, 0.f, 0.f, 0.f};
    for (int k = 0; k < 128; k += 4) {
        const float w0 = W[(k + 0) * 128 + t];
        const float w1 = W[(k + 1) * 128 + t];
        const float w2 = W[(k + 2) * 128 + t];
        const float w3 = W[(k + 3) * 128 + t];
        #pragma unroll
        for (int r = 0; r < 8; ++r) {
            const float4 xv = *reinterpret_cast<const float4*>(&xl[r * 128 + k]);
            acc[r] += xv.x * w0 + xv.y * w1 + xv.z * w2 + xv.w * w3;
        }
    }
    #pragma unroll
    for (int r = 0; r < 8; ++r) xw[r * 128 + t] = acc[r];
    __syncthreads();

    const int b = row0 >> 11, n0 = row0 & 2047;

    bf16x8 st;
    #pragma unroll
    for (int r = 0; r < 8; ++r) st[r] = (__bf16)xw[r * 128 + t];
    *reinterpret_cast<bf16x8*>(&wxT[((size_t)(b * 128 + t)) * 2048 + n0]) = st;

    const int r = t >> 4, h = (t >> 1) & 7, s = t & 1;
    float dot = 0.f;
    #pragma unroll
    for (int d = 0; d < 16; ++d)
        dot += xw[r * 128 + h * 16 + d] * a[h * 32 + s * 16 + d];
    float* dst = s ? ej : ei;
    dst[(b * 8 + h) * 2048 + n0 + r] = dot * LOG2E;
}

__global__ __launch_bounds__(1024, 8)
void gat_kernel(const unsigned long long* __restrict__ bits,
                const unsigned short* __restrict__ wxT,
                const float* __restrict__ ei, const float* __restrict__ ej,
                const float* __restrict__ WoT, const float* __restrict__ bo,
                float* __restrict__ out)
{
    const int tid = threadIdx.x;
    const int w = tid >> 6;          // wave 0..15
    const int h = w & 7;             // head
    const int jh = w >> 3;           // j-half
    const int lane = tid & 63;
    const int r = lane & 15;         // A-frag row / B-frag col
    const int jg = lane >> 4;        // j-octet group
    // XCD-aware bijective swizzle (512 blocks, 8 XCDs -> 64-block chunks)
    const int bid = (blockIdx.x & 7) * 64 + (blockIdx.x >> 3);
    const int b = bid >> 7;
    const int ibase = (bid & 127) << 4;

    __shared__ float hacc[16][128];  // numerator (jh=1), then normalized h
    __shared__ float hsum[8][16];    // denominator (jh=1 partial)

    const float eiv = ei[(b * 8 + h) * 2048 + ibase + r];
    const f32x2 eiv2 = {eiv, eiv};
    const float* ejrow = ej + (b * 8 + h) * 2048;
    const unsigned short* vrow = wxT + ((size_t)(b * 128 + h * 16 + r)) * 2048;
    const unsigned long long* brow = bits + ((size_t)(b * 2048 + ibase + r)) * 32;

    f32x4 acc  = {0.f, 0.f, 0.f, 0.f};
    f32x4 accS = {0.f, 0.f, 0.f, 0.f};
    bf16x8 ones;
    #pragma unroll
    for (int e2 = 0; e2 < 8; ++e2) ones[e2] = (__bf16)1.0f;

    const int jt0 = jh * 1024;
    for (int jt = jt0; jt < jt0 + 1024; jt += 64) {
        const unsigned long long bl = brow[jt >> 6] >> (jg * 8);
        const unsigned int m01[2] = {(unsigned int)bl, (unsigned int)(bl >> 32)};
        #pragma unroll
        for (int kk = 0; kk < 2; ++kk) {
            const int j0 = jt + kk * 32 + jg * 8;
            const float4 e0 = *reinterpret_cast<const float4*>(&ejrow[j0]);
            const float4 e1 = *reinterpret_cast<const float4*>(&ejrow[j0 + 4]);
            const bf16x8 bfr = *reinterpret_cast<const bf16x8*>(&vrow[j0]);
            const unsigned int mk = m01[kk];
            f32x2 zz[4];
            zz[0].x = e0.x; zz[0].y = e0.y;
            zz[1].x = e0.z; zz[1].y = e0.w;
            zz[2].x = e1.x; zz[2].y = e1.y;
            zz[3].x = e1.z; zz[3].y = e1.w;
            bf16x8 afr;
            #pragma unroll
            for (int q = 0; q < 4; ++q) {
                const f32x2 z = zz[q] + eiv2;           // v_pk_add_f32
#if __has_builtin(__builtin_elementwise_max)
                const f32x2 zl = __builtin_elementwise_max(z, z * 0.2f);
#else
                f32x2 zl; zl.x = fmaxf(z.x, 0.2f * z.x); zl.y = fmaxf(z.y, 0.2f * z.y);
#endif
                const float p0 = EXP2F(zl.x);
                const float p1 = EXP2F(zl.y);
                afr[2 * q]     = (__bf16)(((mk >> (2 * q)) & 1u) ? p0 : 0.f);
                afr[2 * q + 1] = (__bf16)(((mk >> (2 * q + 1)) & 1u) ? p1 : 0.f);
            }
            acc  = __builtin_amdgcn_mfma_f32_16x16x32_bf16(afr, bfr,  acc,  0, 0, 0);
            accS = __builtin_amdgcn_mfma_f32_16x16x32_bf16(afr, ones, accS, 0, 0, 0);
        }
    }

    // C/D layout: col = lane&15, row = (lane>>4)*4 + q. accS[q] = partial row sum.
    if (jh == 1) {
        #pragma unroll
        for (int q = 0; q < 4; ++q)
            hacc[jg * 4 + q][h * 16 + r] = acc[q];
        if (r == 0) {
            #pragma unroll
            for (int q = 0; q < 4; ++q) hsum[h][jg * 4 + q] = accS[q];
        }
    }
    __syncthreads();
    if (jh == 0) {
        #pragma unroll
        for (int q = 0; q < 4; ++q) {
            const int row = jg * 4 + q;
            const float num = acc[q] + hacc[row][h * 16 + r];
            const float den = accS[q] + hsum[h][row];
            const float inv = (den > 0.f) ? 1.f / den : 0.f;  // empty row -> 0
            hacc[row][h * 16 + r] = num * inv;
        }
    }
    __syncthreads();

    // ---- fused out-proj + ELU: 1024 threads, 2 rows each
    const int f = tid & 127;
    const int rg = tid >> 7;  // 8 groups x 2 rows
    float o0 = 0.f, o1 = 0.f;
    for (int k = 0; k < 128; k += 4) {
        const float w0 = WoT[(k + 0) * 128 + f];
        const float w1 = WoT[(k + 1) * 128 + f];
        const float w2 = WoT[(k + 2) * 128 + f];
        const float w3 = WoT[(k + 3) * 128 + f];
        const float4 h0 = *reinterpret_cast<const float4*>(&hacc[rg * 2 + 0][k]);
        const float4 h1 = *reinterpret_cast<const float4*>(&hacc[rg * 2 + 1][k]);
        o0 += h0.x * w0 + h0.y * w1 + h0.z * w2 + h0.w * w3;
        o1 += h1.x * w0 + h1.y * w1 + h1.z * w2 + h1.w * w3;
    }
    const float bv = bo[f];
    float vv[2] = {o0 + bv, o1 + bv};
    #pragma unroll
    for (int q = 0; q < 2; ++q) {
        float v = vv[q];
        v = (v > 0.f) ? v : (__expf(v) - 1.f);
        out[(size_t)(b * 2048 + ibase + rg * 2 + q) * 128 + f] = v;
    }
}

extern "C" void kernel_launch(void* const* d_in, const int* in_sizes, int n_in,
                              void* d_out, int out_size, void* d_ws, size_t ws_size,
                              hipStream_t stream) {
    const float* x   = (const float*)d_in[0];
    const int*   adj = (const int*)d_in[1];
    const float* W   = (const float*)d_in[2];
    const float* a   = (const float*)d_in[3];
    const float* Wo  = (const float*)d_in[4];
    const float* bo  = (const float*)d_in[5];
    float* out = (float*)d_out;

    // ws: WxT bf16 (2 MB) | ei (256 KB) | ej (256 KB) | WoT (64 KB) | bits (2 MB)
    char* ws = (char*)d_ws;
    unsigned short* wxT = (unsigned short*)ws;
    float* ei  = (float*)(ws + (size_t)4 * 128 * 2048 * 2);
    float* ej  = ei + 4 * 8 * 2048;
    float* WoT = ej + 4 * 8 * 2048;
    unsigned long long* bits = (unsigned long long*)(WoT + 128 * 128);

    pack_kernel<<<dim3(2048), dim3(256), 0, stream>>>(adj, bits);
    proj_kernel<<<dim3(1025), dim3(128), 0, stream>>>(x, W, a, Wo, wxT, ei, ej, WoT);
    gat_kernel<<<dim3(512), dim3(1024), 0, stream>>>(bits, wxT, ei, ej, WoT, bo, out);
}

// Round 4
// 92.086 us; speedup vs baseline: 1.1265x; 1.1265x over previous
//
#include <hip/hip_runtime.h>
#include <hip/hip_bf16.h>
#include <cstdint>

// GAT fused layer: B=4, N=2048, F=128, H=8, HD=16, all fp32 I/O.
// prep: blocks [0,1025): proj (XW fp32 -> WxT bf16 [B][128][N], ei/ej fp32
//       pre-scaled by log2 e, WoT = Wo^T); blocks [1025,3073): pack adj ->
//       u64 bitmasks [8192][32] (2 MB). Pack is HBM-bound (64 MB); proj
//       blocks launch first and hide under it.
// gat:  block = 16 rows x 8 heads (8 waves, 512 thr, 1 wave/head);
//       register double-buffered j-loop (prefetch next 64-j step while
//       computing current), scores as MFMA A-frags, aggregation + row-sum
//       via mfma_f32_16x16x32_bf16 (B=ones), fused out-proj + ELU.

typedef float f32x2 __attribute__((ext_vector_type(2)));
typedef float f32x4 __attribute__((ext_vector_type(4)));
typedef __bf16 bf16x8 __attribute__((ext_vector_type(8)));

#define LOG2E 1.44269504088896340736f

#if __has_builtin(__builtin_amdgcn_exp2f)
#define EXP2F(x) __builtin_amdgcn_exp2f(x)
#else
#define EXP2F(x) __expf((x) * 0.69314718055994531f)
#endif

__global__ __launch_bounds__(256)
void prep_kernel(const float* __restrict__ x, const float* __restrict__ W,
                 const float* __restrict__ a, const float* __restrict__ Wo,
                 const int* __restrict__ adj,
                 unsigned short* __restrict__ wxT, float* __restrict__ ei,
                 float* __restrict__ ej, float* __restrict__ WoT,
                 unsigned long long* __restrict__ bits)
{
    const int t = threadIdx.x;

    if (blockIdx.x >= 1025) {
        // ---- pack: 2048 blocks x 4 rows
        const int wid = (blockIdx.x - 1025) * 4 + (t >> 6);  // row 0..8191
        const int lane = t & 63;
        const int* row = adj + (size_t)wid * 2048;
        unsigned long long* browp = bits + (size_t)wid * 32;
        #pragma unroll 2
        for (int it = 0; it < 8; ++it) {
            const int base = it * 256;
            const unsigned long long w0 = __ballot(row[base + lane] != 0);
            const unsigned long long w1 = __ballot(row[base + 64 + lane] != 0);
            const unsigned long long w2 = __ballot(row[base + 128 + lane] != 0);
            const unsigned long long w3 = __ballot(row[base + 192 + lane] != 0);
            if (lane == 0) {
                ulonglong2 p0; p0.x = w0; p0.y = w1;
                ulonglong2 p1; p1.x = w2; p1.y = w3;
                *reinterpret_cast<ulonglong2*>(&browp[it * 4])     = p0;
                *reinterpret_cast<ulonglong2*>(&browp[it * 4 + 2]) = p1;
            }
        }
        return;
    }

    // ---- proj: blocks 0..1024, only t<128 active for compute
    const int blk = blockIdx.x;
    if (blk == 1024) {
        if (t < 128)
            for (int k = 0; k < 128; ++k)
                WoT[k * 128 + t] = Wo[t * 128 + k];
        return;
    }
    __shared__ float xl[8 * 128];
    __shared__ float xw[8 * 128];
    const int row0 = blk * 8;
    if (t < 128) {
        #pragma unroll
        for (int r = 0; r < 8; ++r)
            xl[r * 128 + t] = x[(size_t)(row0 + r) * 128 + t];
    }
    __syncthreads();

    if (t < 128) {
        float acc[8] = {0.f, 0.f, 0.f, 0.f, 0.f, 0.f, 0.f, 0.f};
        for (int k = 0; k < 128; k += 4) {
            const float w0 = W[(k + 0) * 128 + t];
            const float w1 = W[(k + 1) * 128 + t];
            const float w2 = W[(k + 2) * 128 + t];
            const float w3 = W[(k + 3) * 128 + t];
            #pragma unroll
            for (int r = 0; r < 8; ++r) {
                const float4 xv = *reinterpret_cast<const float4*>(&xl[r * 128 + k]);
                acc[r] += xv.x * w0 + xv.y * w1 + xv.z * w2 + xv.w * w3;
            }
        }
        #pragma unroll
        for (int r = 0; r < 8; ++r) xw[r * 128 + t] = acc[r];
    }
    __syncthreads();

    if (t < 128) {
        const int b = row0 >> 11, n0 = row0 & 2047;
        bf16x8 st;
        #pragma unroll
        for (int r = 0; r < 8; ++r) st[r] = (__bf16)xw[r * 128 + t];
        *reinterpret_cast<bf16x8*>(&wxT[((size_t)(b * 128 + t)) * 2048 + n0]) = st;

        const int r = t >> 4, h = (t >> 1) & 7, s = t & 1;
        float dot = 0.f;
        #pragma unroll
        for (int d = 0; d < 16; ++d)
            dot += xw[r * 128 + h * 16 + d] * a[h * 32 + s * 16 + d];
        float* dst = s ? ej : ei;
        dst[(b * 8 + h) * 2048 + n0 + r] = dot * LOG2E;
    }
}

__global__ __launch_bounds__(512, 4)
void gat_kernel(const unsigned long long* __restrict__ bits,
                const unsigned short* __restrict__ wxT,
                const float* __restrict__ ei, const float* __restrict__ ej,
                const float* __restrict__ WoT, const float* __restrict__ bo,
                float* __restrict__ out)
{
    const int tid = threadIdx.x;
    const int h = tid >> 6;          // wave = head
    const int lane = tid & 63;
    const int r = lane & 15;         // A-frag row / B-frag col
    const int jg = lane >> 4;        // j-octet group
    // XCD-aware bijective swizzle (512 blocks % 8 == 0)
    const int bid = (blockIdx.x & 7) * 64 + (blockIdx.x >> 3);
    const int b = bid >> 7;
    const int ibase = (bid & 127) << 4;

    __shared__ float hl[16 * 128];

    const float eiv = ei[(b * 8 + h) * 2048 + ibase + r];
    const f32x2 eiv2 = {eiv, eiv};
    const float* ejrow = ej + (b * 8 + h) * 2048;
    const unsigned short* vrow = wxT + ((size_t)(b * 128 + h * 16 + r)) * 2048;
    const unsigned long long* brow = bits + ((size_t)(b * 2048 + ibase + r)) * 32;

    f32x4 acc  = {0.f, 0.f, 0.f, 0.f};
    f32x4 accS = {0.f, 0.f, 0.f, 0.f};
    bf16x8 ones;
    #pragma unroll
    for (int e2 = 0; e2 < 8; ++e2) ones[e2] = (__bf16)1.0f;

    // ---- register double-buffered j-loop: prefetch step jt+64 while computing jt
    const int jaof = jg * 8;
    unsigned long long blC = brow[0];
    float4 eC0 = *reinterpret_cast<const float4*>(&ejrow[jaof]);
    float4 eC1 = *reinterpret_cast<const float4*>(&ejrow[jaof + 4]);
    float4 eC2 = *reinterpret_cast<const float4*>(&ejrow[jaof + 32]);
    float4 eC3 = *reinterpret_cast<const float4*>(&ejrow[jaof + 36]);
    bf16x8 vC0 = *reinterpret_cast<const bf16x8*>(&vrow[jaof]);
    bf16x8 vC1 = *reinterpret_cast<const bf16x8*>(&vrow[jaof + 32]);

    #pragma unroll 2
    for (int jt = 0; jt < 2048; jt += 64) {
        // prefetch next step (wraps to 0 on the last iter; result discarded)
        const int jn = (jt + 64) & 2047;
        const int ja = jn + jaof;
        const unsigned long long blN = brow[jn >> 6];
        const float4 eN0 = *reinterpret_cast<const float4*>(&ejrow[ja]);
        const float4 eN1 = *reinterpret_cast<const float4*>(&ejrow[ja + 4]);
        const float4 eN2 = *reinterpret_cast<const float4*>(&ejrow[ja + 32]);
        const float4 eN3 = *reinterpret_cast<const float4*>(&ejrow[ja + 36]);
        const bf16x8 vN0 = *reinterpret_cast<const bf16x8*>(&vrow[ja]);
        const bf16x8 vN1 = *reinterpret_cast<const bf16x8*>(&vrow[ja + 32]);

        const unsigned long long bl = blC >> (jg * 8);
        const unsigned int mk[2] = {(unsigned int)bl, (unsigned int)(bl >> 32)};
        const float4 ee[4] = {eC0, eC1, eC2, eC3};
        const bf16x8 vv[2] = {vC0, vC1};
        #pragma unroll
        for (int kk = 0; kk < 2; ++kk) {
            const float4 e0 = ee[kk * 2], e1 = ee[kk * 2 + 1];
            const unsigned int m = mk[kk];
            f32x2 zz[4];
            zz[0].x = e0.x; zz[0].y = e0.y;
            zz[1].x = e0.z; zz[1].y = e0.w;
            zz[2].x = e1.x; zz[2].y = e1.y;
            zz[3].x = e1.z; zz[3].y = e1.w;
            bf16x8 afr;
            #pragma unroll
            for (int q = 0; q < 4; ++q) {
                const f32x2 z = zz[q] + eiv2;           // v_pk_add_f32
#if __has_builtin(__builtin_elementwise_max)
                const f32x2 zl = __builtin_elementwise_max(z, z * 0.2f);
#else
                f32x2 zl; zl.x = fmaxf(z.x, 0.2f * z.x); zl.y = fmaxf(z.y, 0.2f * z.y);
#endif
                const float p0 = EXP2F(zl.x);
                const float p1 = EXP2F(zl.y);
                afr[2 * q]     = (__bf16)(((m >> (2 * q)) & 1u) ? p0 : 0.f);
                afr[2 * q + 1] = (__bf16)(((m >> (2 * q + 1)) & 1u) ? p1 : 0.f);
            }
            acc  = __builtin_amdgcn_mfma_f32_16x16x32_bf16(afr, vv[kk], acc,  0, 0, 0);
            accS = __builtin_amdgcn_mfma_f32_16x16x32_bf16(afr, ones,   accS, 0, 0, 0);
        }

        blC = blN;
        eC0 = eN0; eC1 = eN1; eC2 = eN2; eC3 = eN3;
        vC0 = vN0; vC1 = vN1;
    }

    // C/D layout: col = lane&15, row = (lane>>4)*4 + q. accS[q] = full row sum.
    #pragma unroll
    for (int q = 0; q < 4; ++q) {
        const int row = jg * 4 + q;
        const float ls = accS[q];
        const float inv = (ls > 0.f) ? 1.f / ls : 0.f;  // empty row -> 0 (nan_to_num)
        hl[row * 128 + h * 16 + r] = acc[q] * inv;
    }
    __syncthreads();

    // ---- fused out-proj + ELU
    const int f = tid & 127;
    const int rg = tid >> 7;  // 4 groups x 4 rows
    float o0 = 0.f, o1 = 0.f, o2 = 0.f, o3 = 0.f;
    for (int k = 0; k < 128; k += 4) {
        const float w0 = WoT[(k + 0) * 128 + f];
        const float w1 = WoT[(k + 1) * 128 + f];
        const float w2 = WoT[(k + 2) * 128 + f];
        const float w3 = WoT[(k + 3) * 128 + f];
        const float4 h0 = *reinterpret_cast<const float4*>(&hl[(rg * 4 + 0) * 128 + k]);
        const float4 h1 = *reinterpret_cast<const float4*>(&hl[(rg * 4 + 1) * 128 + k]);
        const float4 h2 = *reinterpret_cast<const float4*>(&hl[(rg * 4 + 2) * 128 + k]);
        const float4 h3 = *reinterpret_cast<const float4*>(&hl[(rg * 4 + 3) * 128 + k]);
        o0 += h0.x * w0 + h0.y * w1 + h0.z * w2 + h0.w * w3;
        o1 += h1.x * w0 + h1.y * w1 + h1.z * w2 + h1.w * w3;
        o2 += h2.x * w0 + h2.y * w1 + h2.z * w2 + h2.w * w3;
        o3 += h3.x * w0 + h3.y * w1 + h3.z * w2 + h3.w * w3;
    }
    const float bv = bo[f];
    float vvv[4] = {o0 + bv, o1 + bv, o2 + bv, o3 + bv};
    #pragma unroll
    for (int q = 0; q < 4; ++q) {
        float v = vvv[q];
        v = (v > 0.f) ? v : (__expf(v) - 1.f);
        out[(size_t)(b * 2048 + ibase + rg * 4 + q) * 128 + f] = v;
    }
}

extern "C" void kernel_launch(void* const* d_in, const int* in_sizes, int n_in,
                              void* d_out, int out_size, void* d_ws, size_t ws_size,
                              hipStream_t stream) {
    const float* x   = (const float*)d_in[0];
    const int*   adj = (const int*)d_in[1];
    const float* W   = (const float*)d_in[2];
    const float* a   = (const float*)d_in[3];
    const float* Wo  = (const float*)d_in[4];
    const float* bo  = (const float*)d_in[5];
    float* out = (float*)d_out;

    // ws: WxT bf16 (2 MB) | ei (256 KB) | ej (256 KB) | WoT (64 KB) | bits (2 MB)
    char* ws = (char*)d_ws;
    unsigned short* wxT = (unsigned short*)ws;
    float* ei  = (float*)(ws + (size_t)4 * 128 * 2048 * 2);
    float* ej  = ei + 4 * 8 * 2048;
    float* WoT = ej + 4 * 8 * 2048;
    unsigned long long* bits = (unsigned long long*)(WoT + 128 * 128);

    prep_kernel<<<dim3(1025 + 2048), dim3(256), 0, stream>>>(x, W, a, Wo, adj,
                                                             wxT, ei, ej, WoT, bits);
    gat_kernel<<<dim3(512), dim3(512), 0, stream>>>(bits, wxT, ei, ej, WoT, bo, out);
}